// Round 2
// baseline (708.547 us; speedup 1.0000x reference)
//
#include <hip/hip_runtime.h>
#include <cstdio>
#include <cstdint>

// Problem constants
#define B_  16
#define T_  4096
#define D_  512
#define U_  512
#define KK  1024            // W*D
#define M_  (B_*T_)         // 65536 rows
#define NTOT 1536           // 3 gates * U

// Scan chunking: CHUNK=32 -> 2048 (b,chunk) blocks -> 32 waves/CU resident
// (was CHUNK=128 -> 512 blocks -> 8 waves/CU, latency-bound at 25% occupancy)
#define CHUNK 32
#define NCH   (T_/CHUNK)    // 128 chunks per sequence

typedef __attribute__((ext_vector_type(8))) short  bf16x8;
typedef __attribute__((ext_vector_type(4))) float  f32x4;
typedef __attribute__((ext_vector_type(8))) unsigned short u16x8;

__device__ __forceinline__ unsigned short f2bf(float f) {
    unsigned int u = __float_as_uint(f);
    unsigned int r = (u + 0x7fffu + ((u >> 16) & 1u)) >> 16;   // RNE
    return (unsigned short)r;
}

__device__ __forceinline__ void gl_lds16(const void* g, void* l) {
    __builtin_amdgcn_global_load_lds(
        (const __attribute__((address_space(1))) void*)g,
        (__attribute__((address_space(3))) void*)l, 16, 0, 0);
}

// ---------------------------------------------------------------------------
// Convert x (fp32 [16][4096][512]) -> xz (bf16 [16][4097][512]) with a zero
// row at t=0 per batch (causal pad).
// ---------------------------------------------------------------------------
__global__ __launch_bounds__(256)
void convert_x_kernel(const float* __restrict__ x, unsigned short* __restrict__ xz)
{
    const size_t e = ((size_t)blockIdx.x * 256 + threadIdx.x) * 8;
    const size_t row = e >> 9;                 // 0 .. 16*4097-1
    const int    d   = (int)(e & 511);
    const int    tz  = (int)(row % 4097);
    const size_t b   = row / 4097;
    u16x8 o;
    if (tz == 0) {
        #pragma unroll
        for (int i = 0; i < 8; ++i) o[i] = 0;
    } else {
        const size_t src = (((b << 12) + (size_t)(tz - 1)) << 9) + d;
        const float4 v0 = *reinterpret_cast<const float4*>(x + src);
        const float4 v1 = *reinterpret_cast<const float4*>(x + src + 4);
        o[0] = f2bf(v0.x); o[1] = f2bf(v0.y); o[2] = f2bf(v0.z); o[3] = f2bf(v0.w);
        o[4] = f2bf(v1.x); o[5] = f2bf(v1.y); o[6] = f2bf(v1.z); o[7] = f2bf(v1.w);
    }
    *reinterpret_cast<u16x8*>(xz + e) = o;
}

// ---------------------------------------------------------------------------
// Transpose + convert weights: Wt[(g*512+u)*1024 + k] = Wg[k*512 + u]  (bf16)
// ---------------------------------------------------------------------------
__global__ __launch_bounds__(256)
void convert_wt_kernel(const float* __restrict__ Wz, const float* __restrict__ Wf,
                       const float* __restrict__ Wo, unsigned short* __restrict__ Wt)
{
    __shared__ float tile[32][33];
    const int g = blockIdx.z;
    const float* __restrict__ W = (g == 0) ? Wz : (g == 1 ? Wf : Wo);
    const int k0 = blockIdx.x * 32;
    const int u0 = blockIdx.y * 32;
    const int tx = threadIdx.x, ty = threadIdx.y;
    #pragma unroll
    for (int r = 0; r < 4; ++r)
        tile[ty + r * 8][tx] = W[(size_t)(k0 + ty + r * 8) * 512 + u0 + tx];
    __syncthreads();
    #pragma unroll
    for (int r = 0; r < 4; ++r) {
        const int u = u0 + ty + r * 8;
        Wt[(size_t)(g * 512 + u) * 1024 + k0 + tx] = f2bf(tile[tx][ty + r * 8]);
    }
}

// ---------------------------------------------------------------------------
// bf16 MFMA GEMM + bias + activation.  (unchanged this round)
// Grid: 6144 blocks 1-D, XCD-bijective swizzle (8 XCDs x 768 blocks).
// MFMA operands SWAPPED (A=W, B=x): D rows = u -> float4 stores into [m][u].
// ---------------------------------------------------------------------------
__global__ __launch_bounds__(256)
void gemm_mfma_kernel(const unsigned short* __restrict__ xz,
                      const unsigned short* __restrict__ Wt,
                      const float* __restrict__ bz, const float* __restrict__ bfg,
                      const float* __restrict__ bo,
                      float* __restrict__ zbuf, float* __restrict__ fbuf,
                      float* __restrict__ obuf)
{
    __shared__ unsigned short As[128 * 64];   // 16 KB  (x tile)
    __shared__ unsigned short Bs[128 * 64];   // 16 KB  (W tile)

    const int tid  = threadIdx.x;
    const int lane = tid & 63;
    const int wave = tid >> 6;
    const int wm   = wave >> 1;          // 0..1  (m half)
    const int wn   = wave & 1;           // 0..1  (u half)

    // XCD-bijective swizzle: 6144 = 8 XCDs * 768; nblk fastest within XCD.
    const int flat = blockIdx.x;
    const int xcd  = flat & 7;
    const int idx  = flat >> 3;          // 0..767 (dispatch order on this XCD)
    const int nblk = idx % 12;
    const int mt   = xcd * 64 + idx / 12;
    const int m0   = mt * 128;
    const int n0   = nblk * 128;         // global col in [0,1536)

    // ---- staging address setup ----
    const int swz = (lane & 7) ^ (lane >> 3);      // swizzled 16B-chunk index
    const unsigned short* gA[4];
    const unsigned short* gB[4];
    #pragma unroll
    for (int i = 0; i < 4; ++i) {
        const int r = i * 32 + wave * 8 + (lane >> 3);
        const int m = m0 + r;
        const int b = m >> 12;
        const int t = m & 4095;
        gA[i] = xz + ((size_t)(b * 4097 + t) << 9) + swz * 8;
        gB[i] = Wt + ((size_t)(n0 + r) << 10) + swz * 8;
    }
    char* AsB = (char*)As;
    char* BsB = (char*)Bs;

    f32x4 acc[4][4];
    #pragma unroll
    for (int i = 0; i < 4; ++i)
        #pragma unroll
        for (int j = 0; j < 4; ++j)
            acc[i][j] = (f32x4){0.f, 0.f, 0.f, 0.f};

    // ---- K loop: 16 iterations of BK=64 ----
    for (int kk = 0; kk < 16; ++kk) {
        #pragma unroll
        for (int i = 0; i < 4; ++i)
            gl_lds16(gA[i] + kk * 64, AsB + i * 4096 + wave * 1024);
        #pragma unroll
        for (int i = 0; i < 4; ++i)
            gl_lds16(gB[i] + kk * 64, BsB + i * 4096 + wave * 1024);
        __syncthreads();

        #pragma unroll
        for (int ks = 0; ks < 2; ++ks) {
            const int ch = (ks * 4 + (lane >> 4)) ^ (lane & 7);
            bf16x8 av[4], bv[4];
            // A operand = W rows (u dim)
            #pragma unroll
            for (int i = 0; i < 4; ++i) {
                const int row = wn * 64 + i * 16 + (lane & 15);
                av[i] = *reinterpret_cast<const bf16x8*>(BsB + row * 128 + ch * 16);
            }
            // B operand = x rows (m dim)
            #pragma unroll
            for (int j = 0; j < 4; ++j) {
                const int row = wm * 64 + j * 16 + (lane & 15);
                bv[j] = *reinterpret_cast<const bf16x8*>(AsB + row * 128 + ch * 16);
            }
            #pragma unroll
            for (int i = 0; i < 4; ++i)
                #pragma unroll
                for (int j = 0; j < 4; ++j)
                    acc[i][j] = __builtin_amdgcn_mfma_f32_16x16x32_bf16(
                        av[i], bv[j], acc[i][j], 0, 0, 0);
        }
        __syncthreads();
    }

    // ---- epilogue: bias + activation + float4 stores ----
    const int gate = nblk >> 2;                      // uniform per block
    float* __restrict__ outg = (gate == 0) ? zbuf : (gate == 1 ? fbuf : obuf);
    const float* __restrict__ bg = (gate == 0) ? bz : (gate == 1 ? bfg : bo);
    const int mcol = m0 + wm * 64 + (lane & 15);                 // + j*16
    const int u0g  = (nblk & 3) * 128 + wn * 64 + ((lane >> 4) << 2);  // + i*16

    #pragma unroll
    for (int i = 0; i < 4; ++i) {
        const int u = u0g + i * 16;
        const float4 b4 = *reinterpret_cast<const float4*>(bg + u);
        #pragma unroll
        for (int j = 0; j < 4; ++j) {
            const int m = mcol + j * 16;
            float4 v;
            v.x = acc[i][j][0] + b4.x;
            v.y = acc[i][j][1] + b4.y;
            v.z = acc[i][j][2] + b4.z;
            v.w = acc[i][j][3] + b4.w;
            if (gate == 0) {
                v.x = 2.0f / (1.0f + __expf(-2.0f * v.x)) - 1.0f;
                v.y = 2.0f / (1.0f + __expf(-2.0f * v.y)) - 1.0f;
                v.z = 2.0f / (1.0f + __expf(-2.0f * v.z)) - 1.0f;
                v.w = 2.0f / (1.0f + __expf(-2.0f * v.w)) - 1.0f;
            } else {
                v.x = 1.0f / (1.0f + __expf(-v.x));
                v.y = 1.0f / (1.0f + __expf(-v.y));
                v.z = 1.0f / (1.0f + __expf(-v.z));
                v.w = 1.0f / (1.0f + __expf(-v.w));
            }
            *reinterpret_cast<float4*>(outg + (size_t)m * 512 + u) = v;
        }
    }
}

// ---------------------------------------------------------------------------
// Phase 1: per-chunk affine summary.  One block per (b, chunk); 2048 blocks
// -> 8 blocks/CU x 4 waves = full 32-wave occupancy; 32-long serial loop.
// ---------------------------------------------------------------------------
__global__ __launch_bounds__(256)
void chunk_summary_kernel(const float* __restrict__ fbuf,
                          const float* __restrict__ zbuf,
                          float* __restrict__ Ach, float* __restrict__ Bch)
{
    const int bc = blockIdx.x;           // 0..2047
    const int c  = bc & (NCH - 1);
    const int b  = bc >> 7;              // NCH = 128
    const int u  = threadIdx.x * 2;

    const long long base = ((long long)(b * T_ + c * CHUNK)) * U_ + u;
    float2 A = make_float2(1.0f, 1.0f);
    float2 Bv = make_float2(0.0f, 0.0f);
    #pragma unroll 8
    for (int i = 0; i < CHUNK; ++i) {
        const float2 f = *reinterpret_cast<const float2*>(fbuf + base + (long long)i * U_);
        const float2 z = *reinterpret_cast<const float2*>(zbuf + base + (long long)i * U_);
        Bv.x = f.x * Bv.x + (1.0f - f.x) * z.x;
        Bv.y = f.y * Bv.y + (1.0f - f.y) * z.y;
        A.x *= f.x;
        A.y *= f.y;
    }
    const int idx = (b * NCH + c) * U_ + u;
    *reinterpret_cast<float2*>(Ach + idx) = A;
    *reinterpret_cast<float2*>(Bch + idx) = Bv;
}

// ---------------------------------------------------------------------------
// Phase 2: exclusive prefix over chunks per (b,u). float2 per thread.
// grid: 16 blocks x 256 threads = 4096 threads x 2 u = 8192 (b,u) pairs.
// NCH=128 serial iters; loads are address-independent -> unroll-8 prefetch.
// ---------------------------------------------------------------------------
__global__ __launch_bounds__(256)
void chunk_prefix_kernel(const float* __restrict__ Ach,
                         const float* __restrict__ Bch,
                         float* __restrict__ Hin)
{
    const int g = blockIdx.x * 256 + threadIdx.x;   // 0..4095
    const int b = g >> 8;
    const int u = (g & 255) * 2;
    float2 h = make_float2(0.0f, 0.0f);
    #pragma unroll 8
    for (int c = 0; c < NCH; ++c) {
        const int idx = (b * NCH + c) * U_ + u;
        *reinterpret_cast<float2*>(Hin + idx) = h;
        const float2 A = *reinterpret_cast<const float2*>(Ach + idx);
        const float2 Bv = *reinterpret_cast<const float2*>(Bch + idx);
        h.x = A.x * h.x + Bv.x;
        h.y = A.y * h.y + Bv.y;
    }
}

// ---------------------------------------------------------------------------
// Phase 3: apply scan within chunk, multiply by o, write output. 2048 blocks.
// ---------------------------------------------------------------------------
__global__ __launch_bounds__(256)
void scan_apply_kernel(const float* __restrict__ fbuf,
                       const float* __restrict__ zbuf,
                       const float* __restrict__ obuf,
                       const float* __restrict__ Hin,
                       float* __restrict__ out)
{
    const int bc = blockIdx.x;           // 0..2047
    const int c  = bc & (NCH - 1);
    const int b  = bc >> 7;
    const int u  = threadIdx.x * 2;

    const long long base = ((long long)(b * T_ + c * CHUNK)) * U_ + u;
    float2 h = *reinterpret_cast<const float2*>(Hin + (b * NCH + c) * U_ + u);
    #pragma unroll 8
    for (int i = 0; i < CHUNK; ++i) {
        const long long p = base + (long long)i * U_;
        const float2 f = *reinterpret_cast<const float2*>(fbuf + p);
        const float2 z = *reinterpret_cast<const float2*>(zbuf + p);
        const float2 o = *reinterpret_cast<const float2*>(obuf + p);
        h.x = f.x * h.x + (1.0f - f.x) * z.x;
        h.y = f.y * h.y + (1.0f - f.y) * z.y;
        float2 r;
        r.x = o.x * h.x;
        r.y = o.y * h.y;
        *reinterpret_cast<float2*>(out + p) = r;
    }
}

// ---------------------------------------------------------------------------
extern "C" void kernel_launch(void* const* d_in, const int* in_sizes, int n_in,
                              void* d_out, int out_size, void* d_ws, size_t ws_size,
                              hipStream_t stream)
{
    const float* x  = (const float*)d_in[0];
    const float* Wz = (const float*)d_in[1];
    const float* bz = (const float*)d_in[2];
    const float* Wf = (const float*)d_in[3];
    const float* bf = (const float*)d_in[4];
    const float* Wo = (const float*)d_in[5];
    const float* bo = (const float*)d_in[6];
    float* out = (float*)d_out;

    const size_t S  = (size_t)M_ * U_;            // 33,554,432 per gate buffer
    const size_t Sc = (size_t)B_ * NCH * U_;      // 1,048,576 per chunk buffer
    const size_t XZ = (size_t)B_ * (T_ + 1) * D_; // 33,562,624 bf16 elems
    const size_t WT = (size_t)NTOT * KK;          // 1,572,864 bf16 elems

    float* zbuf = (float*)d_ws;
    float* fbuf = zbuf + S;
    float* obuf = fbuf + S;
    unsigned short* xz = (unsigned short*)(obuf + S);
    unsigned short* Wt = xz + XZ;
    float* Ach = (float*)(Wt + WT);
    float* Bch = Ach + Sc;
    float* Hin = Bch + Sc;

    const size_t need = 3 * S * sizeof(float) + (XZ + WT) * sizeof(unsigned short)
                      + 3 * Sc * sizeof(float);
    if (ws_size < need) {
        fprintf(stderr, "QRNN kernel: ws_size=%zu < needed %zu bytes!\n",
                ws_size, need);
    }

    // 1. converts
    {
        const size_t nthreads = XZ / 8;                   // 4,195,328
        convert_x_kernel<<<dim3((unsigned)(nthreads / 256)), 256, 0, stream>>>(x, xz);
        convert_wt_kernel<<<dim3(32, 16, 3), dim3(32, 8), 0, stream>>>(Wz, Wf, Wo, Wt);
    }
    // 2. fused bf16 MFMA GEMM + activations (XCD-swizzled 1-D grid)
    gemm_mfma_kernel<<<dim3(12 * (M_ / 128)), 256, 0, stream>>>(
        xz, Wt, bz, bf, bo, zbuf, fbuf, obuf);
    // 3. scan
    chunk_summary_kernel<<<dim3(B_ * NCH), 256, 0, stream>>>(fbuf, zbuf, Ach, Bch);
    chunk_prefix_kernel<<<dim3(16), 256, 0, stream>>>(Ach, Bch, Hin);
    scan_apply_kernel<<<dim3(B_ * NCH), 256, 0, stream>>>(fbuf, zbuf, obuf, Hin, out);
}

// Round 4
// 668.050 us; speedup vs baseline: 1.0606x; 1.0606x over previous
//
#include <hip/hip_runtime.h>
#include <cstdio>
#include <cstdint>

// Problem constants
#define B_  16
#define T_  4096
#define D_  512
#define U_  512
#define KK  1024            // W*D
#define M_  (B_*T_)         // 65536 rows
#define NTOT 1536           // 3 gates * U

// Scan chunking (round-1 measured config)
#define CHUNK 128
#define NCH   (T_/CHUNK)    // 32 chunks per sequence

typedef __attribute__((ext_vector_type(8))) short  bf16x8;
typedef __attribute__((ext_vector_type(4))) float  f32x4;
typedef __attribute__((ext_vector_type(8))) unsigned short u16x8;

__device__ __forceinline__ unsigned short f2bf(float f) {
    unsigned int u = __float_as_uint(f);
    unsigned int r = (u + 0x7fffu + ((u >> 16) & 1u)) >> 16;   // RNE
    return (unsigned short)r;
}

__device__ __forceinline__ void gl_lds16(const void* g, void* l) {
    __builtin_amdgcn_global_load_lds(
        (const __attribute__((address_space(1))) void*)g,
        (__attribute__((address_space(3))) void*)l, 16, 0, 0);
}

// ---------------------------------------------------------------------------
// Convert x (fp32 [16][4096][512]) -> xz (bf16 [16][4097][512]) with a zero
// row at t=0 per batch (causal pad).
// ---------------------------------------------------------------------------
__global__ __launch_bounds__(256)
void convert_x_kernel(const float* __restrict__ x, unsigned short* __restrict__ xz)
{
    const size_t e = ((size_t)blockIdx.x * 256 + threadIdx.x) * 8;
    const size_t row = e >> 9;                 // 0 .. 16*4097-1
    const int    d   = (int)(e & 511);
    const int    tz  = (int)(row % 4097);
    const size_t b   = row / 4097;
    u16x8 o;
    if (tz == 0) {
        #pragma unroll
        for (int i = 0; i < 8; ++i) o[i] = 0;
    } else {
        const size_t src = (((b << 12) + (size_t)(tz - 1)) << 9) + d;
        const float4 v0 = *reinterpret_cast<const float4*>(x + src);
        const float4 v1 = *reinterpret_cast<const float4*>(x + src + 4);
        o[0] = f2bf(v0.x); o[1] = f2bf(v0.y); o[2] = f2bf(v0.z); o[3] = f2bf(v0.w);
        o[4] = f2bf(v1.x); o[5] = f2bf(v1.y); o[6] = f2bf(v1.z); o[7] = f2bf(v1.w);
    }
    *reinterpret_cast<u16x8*>(xz + e) = o;
}

// ---------------------------------------------------------------------------
// Transpose + convert weights: Wt[(g*512+u)*1024 + k] = Wg[k*512 + u]  (bf16)
// ---------------------------------------------------------------------------
__global__ __launch_bounds__(256)
void convert_wt_kernel(const float* __restrict__ Wz, const float* __restrict__ Wf,
                       const float* __restrict__ Wo, unsigned short* __restrict__ Wt)
{
    __shared__ float tile[32][33];
    const int g = blockIdx.z;
    const float* __restrict__ W = (g == 0) ? Wz : (g == 1 ? Wf : Wo);
    const int k0 = blockIdx.x * 32;
    const int u0 = blockIdx.y * 32;
    const int tx = threadIdx.x, ty = threadIdx.y;
    #pragma unroll
    for (int r = 0; r < 4; ++r)
        tile[ty + r * 8][tx] = W[(size_t)(k0 + ty + r * 8) * 512 + u0 + tx];
    __syncthreads();
    #pragma unroll
    for (int r = 0; r < 4; ++r) {
        const int u = u0 + ty + r * 8;
        Wt[(size_t)(g * 512 + u) * 1024 + k0 + tx] = f2bf(tile[tx][ty + r * 8]);
    }
}

// ---------------------------------------------------------------------------
// bf16 MFMA GEMM + bias + activation.  256x256 tile, BK=64, 8 waves,
// double-buffered LDS (128 KB), counted-vmcnt pipeline:
//   prologue: STAGE(0->buf0), STAGE(1->buf1)            (16 loads in flight)
//   loop t:   vmcnt(8)  -> tile t resident (t+1 still in flight)
//             s_barrier -> all waves' loads for t landed
//             24 ds_read_b128 + 64 MFMA (setprio 1)
//             s_barrier -> all waves done reading buf[t&1]
//             STAGE(t+2 -> buf[t&1])                    (8 loads re-issued)
// Never vmcnt(0) in the main loop; __syncthreads (which drains vmcnt) unused.
// Grid 1536 = 8 XCD x 192; n fastest within XCD (A-panel L2 reuse).
// MFMA operands swapped (A=W, B=x) -> lane's 4 acc regs = 4 consecutive u.
// ---------------------------------------------------------------------------
__global__ __launch_bounds__(512, 2)
void gemm_mfma_kernel(const unsigned short* __restrict__ xz,
                      const unsigned short* __restrict__ Wt,
                      const float* __restrict__ bz, const float* __restrict__ bfg,
                      const float* __restrict__ bo,
                      float* __restrict__ zbuf, float* __restrict__ fbuf,
                      float* __restrict__ obuf)
{
    __shared__ unsigned short As[2 * 256 * 64];   // x tile,  2 bufs x 32 KB
    __shared__ unsigned short Bs[2 * 256 * 64];   // W tile,  2 bufs x 32 KB

    const int tid  = threadIdx.x;
    const int lane = tid & 63;
    const int wave = tid >> 6;           // 0..7
    const int wu   = wave & 3;           // u-quarter (0..3)
    const int wm   = wave >> 2;          // m-half    (0..1)

    // XCD-bijective swizzle: 1536 = 8 * 192; ntile fastest within XCD.
    const int flat  = blockIdx.x;
    const int xcd   = flat & 7;
    const int idx   = flat >> 3;         // 0..191
    const int ntile = idx % 6;
    const int mt    = xcd * 32 + idx / 6;
    const int m0 = mt * 256;
    const int n0 = ntile * 256;          // global col in [0,1536)
    const int b  = m0 >> 12;             // uniform per block (256 | 4096)
    const int t0 = m0 & 4095;

    // ---- staging addresses (pre-swizzled global source, linear LDS dest) ----
    const int srow = wave * 8 + (lane >> 3);          // row within 64-row round
    const int swz  = (lane & 7) ^ (lane >> 3);        // 16B-chunk index
    const unsigned short* gA = xz + ((size_t)(b * 4097 + t0 + srow) << 9) + swz * 8;
    const unsigned short* gB = Wt + ((size_t)(n0 + srow) << 10) + swz * 8;
    char* AsB = (char*)As;
    char* BsB = (char*)Bs;
    const int ldst = wave * 1024;        // per-wave dest offset within a round

    auto STAGE = [&](int kt, int bf) {
        #pragma unroll
        for (int i = 0; i < 4; ++i)      // A: rows i*64.., stride 512 elems/row
            gl_lds16(gA + i * 32768 + kt * 64, AsB + bf * 32768 + i * 8192 + ldst);
        #pragma unroll
        for (int i = 0; i < 4; ++i)      // B: rows i*64.., stride 1024 elems/row
            gl_lds16(gB + i * 65536 + kt * 64, BsB + bf * 32768 + i * 8192 + ldst);
    };

    f32x4 acc[4][8];
    #pragma unroll
    for (int i = 0; i < 4; ++i)
        #pragma unroll
        for (int j = 0; j < 8; ++j)
            acc[i][j] = (f32x4){0.f, 0.f, 0.f, 0.f};

    // ---- read-side precomputed offsets (proven conflict-free XOR layout) ----
    const int l15 = lane & 15;
    const int ck0 = (((lane >> 4) + 0) ^ (lane & 7)) * 16;   // kk=0 chunk
    const int ck1 = (((lane >> 4) + 4) ^ (lane & 7)) * 16;   // kk=1 chunk
    const int wvBase = (wu * 64 + l15) * 128;                // W rows (u)
    const int xvBase = (wm * 128 + l15) * 128;               // x rows (m)

    auto COMPUTE = [&](int bf) {
        const char* AB = AsB + bf * 32768;
        const char* BB = BsB + bf * 32768;
        bf16x8 wv[4][2];
        #pragma unroll
        for (int i = 0; i < 4; ++i) {
            wv[i][0] = *reinterpret_cast<const bf16x8*>(BB + wvBase + i * 2048 + ck0);
            wv[i][1] = *reinterpret_cast<const bf16x8*>(BB + wvBase + i * 2048 + ck1);
        }
        #pragma unroll
        for (int jh = 0; jh < 2; ++jh) {
            bf16x8 xv[4][2];
            #pragma unroll
            for (int j2 = 0; j2 < 4; ++j2) {
                xv[j2][0] = *reinterpret_cast<const bf16x8*>(
                    AB + xvBase + (jh * 4 + j2) * 2048 + ck0);
                xv[j2][1] = *reinterpret_cast<const bf16x8*>(
                    AB + xvBase + (jh * 4 + j2) * 2048 + ck1);
            }
            __builtin_amdgcn_s_setprio(1);
            #pragma unroll
            for (int i = 0; i < 4; ++i)
                #pragma unroll
                for (int j2 = 0; j2 < 4; ++j2) {
                    acc[i][jh * 4 + j2] = __builtin_amdgcn_mfma_f32_16x16x32_bf16(
                        wv[i][0], xv[j2][0], acc[i][jh * 4 + j2], 0, 0, 0);
                    acc[i][jh * 4 + j2] = __builtin_amdgcn_mfma_f32_16x16x32_bf16(
                        wv[i][1], xv[j2][1], acc[i][jh * 4 + j2], 0, 0, 0);
                }
            __builtin_amdgcn_s_setprio(0);
        }
    };

    // ---- pipelined K loop: 16 K-tiles of BK=64 ----
    STAGE(0, 0);
    STAGE(1, 1);

    #pragma unroll 1
    for (int t = 0; t < 15; ++t) {
        asm volatile("s_waitcnt vmcnt(8)" ::: "memory");
        __builtin_amdgcn_s_barrier();
        asm volatile("" ::: "memory");
        COMPUTE(t & 1);
        asm volatile("" ::: "memory");
        __builtin_amdgcn_s_barrier();
        asm volatile("" ::: "memory");
        if (t < 14) STAGE(t + 2, t & 1);
    }
    asm volatile("s_waitcnt vmcnt(0)" ::: "memory");
    __builtin_amdgcn_s_barrier();
    asm volatile("" ::: "memory");
    COMPUTE(1);

    // ---- epilogue: bias + activation + float4 stores ----
    // D layout: col = lane&15 -> m; row = (lane>>4)*4+reg -> u (4 consecutive)
    const int gate = ntile >> 1;                     // uniform per block
    float* __restrict__ outg = (gate == 0) ? zbuf : (gate == 1 ? fbuf : obuf);
    const float* __restrict__ bg = (gate == 0) ? bz : (gate == 1 ? bfg : bo);
    const int ubase = (ntile & 1) * 256 + wu * 64 + ((lane >> 4) << 2);
    const int mbase = m0 + wm * 128 + l15;

    #pragma unroll
    for (int i = 0; i < 4; ++i) {
        const int u = ubase + i * 16;
        const float4 b4 = *reinterpret_cast<const float4*>(bg + u);
        #pragma unroll
        for (int j = 0; j < 8; ++j) {
            const int m = mbase + j * 16;
            float4 v;
            v.x = acc[i][j][0] + b4.x;
            v.y = acc[i][j][1] + b4.y;
            v.z = acc[i][j][2] + b4.z;
            v.w = acc[i][j][3] + b4.w;
            if (gate == 0) {
                v.x = 2.0f / (1.0f + __expf(-2.0f * v.x)) - 1.0f;
                v.y = 2.0f / (1.0f + __expf(-2.0f * v.y)) - 1.0f;
                v.z = 2.0f / (1.0f + __expf(-2.0f * v.z)) - 1.0f;
                v.w = 2.0f / (1.0f + __expf(-2.0f * v.w)) - 1.0f;
            } else {
                v.x = 1.0f / (1.0f + __expf(-v.x));
                v.y = 1.0f / (1.0f + __expf(-v.y));
                v.z = 1.0f / (1.0f + __expf(-v.z));
                v.w = 1.0f / (1.0f + __expf(-v.w));
            }
            *reinterpret_cast<float4*>(outg + (size_t)m * 512 + u) = v;
        }
    }
}

// ---------------------------------------------------------------------------
// Phase 1: per-chunk affine summary.  One block per (b, chunk); each thread
// handles 2 consecutive u via float2 (2 KB contiguous per wave-row).
// ---------------------------------------------------------------------------
__global__ __launch_bounds__(256)
void chunk_summary_kernel(const float* __restrict__ fbuf,
                          const float* __restrict__ zbuf,
                          float* __restrict__ Ach, float* __restrict__ Bch)
{
    const int bc = blockIdx.x;           // 0..511
    const int c  = bc & (NCH - 1);
    const int b  = bc >> 5;              // NCH = 32
    const int u  = threadIdx.x * 2;

    const long long base = ((long long)(b * T_ + c * CHUNK)) * U_ + u;
    float2 A = make_float2(1.0f, 1.0f);
    float2 Bv = make_float2(0.0f, 0.0f);
    #pragma unroll 8
    for (int i = 0; i < CHUNK; ++i) {
        const float2 f = *reinterpret_cast<const float2*>(fbuf + base + (long long)i * U_);
        const float2 z = *reinterpret_cast<const float2*>(zbuf + base + (long long)i * U_);
        Bv.x = f.x * Bv.x + (1.0f - f.x) * z.x;
        Bv.y = f.y * Bv.y + (1.0f - f.y) * z.y;
        A.x *= f.x;
        A.y *= f.y;
    }
    const int idx = (b * NCH + c) * U_ + u;
    *reinterpret_cast<float2*>(Ach + idx) = A;
    *reinterpret_cast<float2*>(Bch + idx) = Bv;
}

// ---------------------------------------------------------------------------
// Phase 2: exclusive prefix over chunks per (b,u). float2 per thread.
// grid: 16 blocks x 256 threads = 4096 threads x 2 u = 8192 (b,u) pairs.
// ---------------------------------------------------------------------------
__global__ __launch_bounds__(256)
void chunk_prefix_kernel(const float* __restrict__ Ach,
                         const float* __restrict__ Bch,
                         float* __restrict__ Hin)
{
    const int g = blockIdx.x * 256 + threadIdx.x;   // 0..4095
    const int b = g >> 8;
    const int u = (g & 255) * 2;
    float2 h = make_float2(0.0f, 0.0f);
    #pragma unroll 4
    for (int c = 0; c < NCH; ++c) {
        const int idx = (b * NCH + c) * U_ + u;
        *reinterpret_cast<float2*>(Hin + idx) = h;
        const float2 A = *reinterpret_cast<const float2*>(Ach + idx);
        const float2 Bv = *reinterpret_cast<const float2*>(Bch + idx);
        h.x = A.x * h.x + Bv.x;
        h.y = A.y * h.y + Bv.y;
    }
}

// ---------------------------------------------------------------------------
// Phase 3: apply scan within chunk, multiply by o, write output. float2.
// ---------------------------------------------------------------------------
__global__ __launch_bounds__(256)
void scan_apply_kernel(const float* __restrict__ fbuf,
                       const float* __restrict__ zbuf,
                       const float* __restrict__ obuf,
                       const float* __restrict__ Hin,
                       float* __restrict__ out)
{
    const int bc = blockIdx.x;           // 0..511
    const int c  = bc & (NCH - 1);
    const int b  = bc >> 5;
    const int u  = threadIdx.x * 2;

    const long long base = ((long long)(b * T_ + c * CHUNK)) * U_ + u;
    float2 h = *reinterpret_cast<const float2*>(Hin + (b * NCH + c) * U_ + u);
    #pragma unroll 8
    for (int i = 0; i < CHUNK; ++i) {
        const long long p = base + (long long)i * U_;
        const float2 f = *reinterpret_cast<const float2*>(fbuf + p);
        const float2 z = *reinterpret_cast<const float2*>(zbuf + p);
        const float2 o = *reinterpret_cast<const float2*>(obuf + p);
        h.x = f.x * h.x + (1.0f - f.x) * z.x;
        h.y = f.y * h.y + (1.0f - f.y) * z.y;
        float2 r;
        r.x = o.x * h.x;
        r.y = o.y * h.y;
        *reinterpret_cast<float2*>(out + p) = r;
    }
}

// ---------------------------------------------------------------------------
extern "C" void kernel_launch(void* const* d_in, const int* in_sizes, int n_in,
                              void* d_out, int out_size, void* d_ws, size_t ws_size,
                              hipStream_t stream)
{
    const float* x  = (const float*)d_in[0];
    const float* Wz = (const float*)d_in[1];
    const float* bz = (const float*)d_in[2];
    const float* Wf = (const float*)d_in[3];
    const float* bf = (const float*)d_in[4];
    const float* Wo = (const float*)d_in[5];
    const float* bo = (const float*)d_in[6];
    float* out = (float*)d_out;

    const size_t S  = (size_t)M_ * U_;            // 33,554,432 per gate buffer
    const size_t Sc = (size_t)B_ * NCH * U_;      // 262,144 per chunk buffer
    const size_t XZ = (size_t)B_ * (T_ + 1) * D_; // 33,562,624 bf16 elems
    const size_t WT = (size_t)NTOT * KK;          // 1,572,864 bf16 elems

    float* zbuf = (float*)d_ws;
    float* fbuf = zbuf + S;
    float* obuf = fbuf + S;
    unsigned short* xz = (unsigned short*)(obuf + S);
    unsigned short* Wt = xz + XZ;
    float* Ach = (float*)(Wt + WT);
    float* Bch = Ach + Sc;
    float* Hin = Bch + Sc;

    const size_t need = 3 * S * sizeof(float) + (XZ + WT) * sizeof(unsigned short)
                      + 3 * Sc * sizeof(float);
    if (ws_size < need) {
        fprintf(stderr, "QRNN kernel: ws_size=%zu < needed %zu bytes!\n",
                ws_size, need);
    }

    // 1. converts
    {
        const size_t nthreads = XZ / 8;                   // 4,195,328
        convert_x_kernel<<<dim3((unsigned)(nthreads / 256)), 256, 0, stream>>>(x, xz);
        convert_wt_kernel<<<dim3(32, 16, 3), dim3(32, 8), 0, stream>>>(Wz, Wf, Wo, Wt);
    }
    // 2. pipelined bf16 MFMA GEMM + activations (256^2 tile, 512 threads)
    gemm_mfma_kernel<<<dim3(6 * (M_ / 256)), 512, 0, stream>>>(
        xz, Wt, bz, bf, bo, zbuf, fbuf, obuf);
    // 3. scan
    chunk_summary_kernel<<<dim3(B_ * NCH), 256, 0, stream>>>(fbuf, zbuf, Ach, Bch);
    chunk_prefix_kernel<<<dim3(16), 256, 0, stream>>>(Ach, Bch, Hin);
    scan_apply_kernel<<<dim3(B_ * NCH), 256, 0, stream>>>(fbuf, zbuf, obuf, Hin, out);
}

// Round 5
// 656.000 us; speedup vs baseline: 1.0801x; 1.0184x over previous
//
#include <hip/hip_runtime.h>
#include <cstdio>
#include <cstdint>

// Problem constants
#define B_  16
#define T_  4096
#define D_  512
#define U_  512
#define KK  1024            // W*D
#define M_  (B_*T_)         // 65536 rows
#define NTOT 1536           // 3 gates * U

// Scan chunking (round-1 measured config)
#define CHUNK 128
#define NCH   (T_/CHUNK)    // 32 chunks per sequence

typedef __attribute__((ext_vector_type(8))) short  bf16x8;
typedef __attribute__((ext_vector_type(4))) float  f32x4;
typedef __attribute__((ext_vector_type(8))) unsigned short u16x8;

__device__ __forceinline__ unsigned short f2bf(float f) {
    unsigned int u = __float_as_uint(f);
    unsigned int r = (u + 0x7fffu + ((u >> 16) & 1u)) >> 16;   // RNE
    return (unsigned short)r;
}

__device__ __forceinline__ void gl_lds16(const void* g, void* l) {
    __builtin_amdgcn_global_load_lds(
        (const __attribute__((address_space(1))) void*)g,
        (__attribute__((address_space(3))) void*)l, 16, 0, 0);
}

// ---------------------------------------------------------------------------
// Convert x (fp32 [16][4096][512]) -> xz (bf16 [16][4097][512]) with a zero
// row at t=0 per batch (causal pad).
// ---------------------------------------------------------------------------
__global__ __launch_bounds__(256)
void convert_x_kernel(const float* __restrict__ x, unsigned short* __restrict__ xz)
{
    const size_t e = ((size_t)blockIdx.x * 256 + threadIdx.x) * 8;
    const size_t row = e >> 9;                 // 0 .. 16*4097-1
    const int    d   = (int)(e & 511);
    const int    tz  = (int)(row % 4097);
    const size_t b   = row / 4097;
    u16x8 o;
    if (tz == 0) {
        #pragma unroll
        for (int i = 0; i < 8; ++i) o[i] = 0;
    } else {
        const size_t src = (((b << 12) + (size_t)(tz - 1)) << 9) + d;
        const float4 v0 = *reinterpret_cast<const float4*>(x + src);
        const float4 v1 = *reinterpret_cast<const float4*>(x + src + 4);
        o[0] = f2bf(v0.x); o[1] = f2bf(v0.y); o[2] = f2bf(v0.z); o[3] = f2bf(v0.w);
        o[4] = f2bf(v1.x); o[5] = f2bf(v1.y); o[6] = f2bf(v1.z); o[7] = f2bf(v1.w);
    }
    *reinterpret_cast<u16x8*>(xz + e) = o;
}

// ---------------------------------------------------------------------------
// Transpose + convert weights: Wt[(g*512+u)*1024 + k] = Wg[k*512 + u]  (bf16)
// ---------------------------------------------------------------------------
__global__ __launch_bounds__(256)
void convert_wt_kernel(const float* __restrict__ Wz, const float* __restrict__ Wf,
                       const float* __restrict__ Wo, unsigned short* __restrict__ Wt)
{
    __shared__ float tile[32][33];
    const int g = blockIdx.z;
    const float* __restrict__ W = (g == 0) ? Wz : (g == 1 ? Wf : Wo);
    const int k0 = blockIdx.x * 32;
    const int u0 = blockIdx.y * 32;
    const int tx = threadIdx.x, ty = threadIdx.y;
    #pragma unroll
    for (int r = 0; r < 4; ++r)
        tile[ty + r * 8][tx] = W[(size_t)(k0 + ty + r * 8) * 512 + u0 + tx];
    __syncthreads();
    #pragma unroll
    for (int r = 0; r < 4; ++r) {
        const int u = u0 + ty + r * 8;
        Wt[(size_t)(g * 512 + u) * 1024 + k0 + tx] = f2bf(tile[tx][ty + r * 8]);
    }
}

// ---------------------------------------------------------------------------
// bf16 MFMA GEMM + bias + activation.  256x256 tile, 8 waves.
// 4-slot ring pipeline at 32-k granularity (unit = A 16KB + B 16KB = 32KB):
//   prologue: STAGE(0), STAGE(1), STAGE(2)              (12 loads in flight)
//   phase tau (0..31):
//     vmcnt(8)   -> unit tau resident (tau+1, tau+2 still in flight)
//     s_barrier  -> all waves' unit-tau loads landed; slot (tau-1)&3 dead
//     STAGE(tau+3) into slot (tau+3)&3 = (tau-1)&3      (4 loads re-issued)
//     12 ds_read_b128 + 32 MFMA (setprio 1)
// Prefetch lead = 3 phases (~1000cy) -> covers HBM miss; never vmcnt(0)
// in the main loop; one barrier per phase.
// LDS pair-row XOR layout: unit stored as [128 pair-rows][8 x 16B granules],
// granule pos ^= (pair_row & 7): ds_read_b128 is 2-way (free) bank-aliased;
// staging is linear-dest (gl_lds) with inverse-swizzled global source.
// Grid 1536 = 8 XCD x 192; ntile fastest within XCD (A-panel L2 reuse).
// MFMA operands swapped (A=W, B=x) -> lane's 4 acc regs = 4 consecutive u.
// ---------------------------------------------------------------------------
__global__ __launch_bounds__(512, 1)
void gemm_mfma_kernel(const unsigned short* __restrict__ xz,
                      const unsigned short* __restrict__ Wt,
                      const float* __restrict__ bz, const float* __restrict__ bfg,
                      const float* __restrict__ bo,
                      float* __restrict__ zbuf, float* __restrict__ fbuf,
                      float* __restrict__ obuf)
{
    __shared__ unsigned short lds[4 * 16384];     // 4 slots x 32 KB = 128 KB
    char* L = (char*)lds;

    const int tid  = threadIdx.x;
    const int lane = tid & 63;
    const int wave = tid >> 6;           // 0..7
    const int wu   = wave & 3;           // u-quarter (0..3)
    const int wm   = wave >> 2;          // m-half    (0..1)

    // XCD-bijective swizzle: 1536 = 8 * 192; ntile fastest within XCD.
    const int flat  = blockIdx.x;
    const int xcd   = flat & 7;
    const int idx   = flat >> 3;         // 0..191
    const int ntile = idx % 6;
    const int mt    = xcd * 32 + idx / 6;
    const int m0 = mt * 256;
    const int n0 = ntile * 256;          // global col in [0,1536)
    const int b  = m0 >> 12;             // uniform per block (256 | 4096)
    const int t0 = m0 & 4095;

    // ---- staging sources: granule g = l*512 + tid; LDS dest = g*16 (linear).
    // g -> (row, src granule): pr=g>>3, p=g&7, e=p^(pr&7), row=2*pr+(e>>2),
    // c=e&3.  (inverse of the read-side XOR; involution verified.)
    const unsigned short* srcA[2];
    const unsigned short* srcB[2];
    #pragma unroll
    for (int l = 0; l < 2; ++l) {
        const int g  = l * 512 + tid;
        const int pr = g >> 3, p = g & 7;
        const int e  = p ^ (pr & 7);
        const int r  = pr * 2 + (e >> 2);
        const int c  = e & 3;
        srcA[l] = xz + ((size_t)(b * 4097 + t0 + r) << 9) + c * 8;
        srcB[l] = Wt + ((size_t)(n0 + r) << 10) + c * 8;
    }
    const int dstOff = tid * 16;

    auto STAGE = [&](int tau) {
        char* s = L + (tau & 3) * 32768;
        const int ko = tau * 32;                          // k elems
        gl_lds16(srcA[0] + ko, s + dstOff);               // A rows 0..255
        gl_lds16(srcA[1] + ko, s + 8192  + dstOff);
        gl_lds16(srcB[0] + ko, s + 16384 + dstOff);       // B rows 0..255
        gl_lds16(srcB[1] + ko, s + 24576 + dstOff);
    };

    f32x4 acc[4][8];
    #pragma unroll
    for (int i = 0; i < 4; ++i)
        #pragma unroll
        for (int j = 0; j < 8; ++j)
            acc[i][j] = (f32x4){0.f, 0.f, 0.f, 0.f};

    // ---- read-side bases (pair-row XOR layout) ----
    const int h     = (lane >> 1) & 7;                    // pair-row low bits
    const int pos16 = ((((lane & 1) << 2) | (lane >> 4)) ^ h) << 4;
    const int aBase = ((wm * 64 + h) << 7) + pos16;               // x (m rows)
    const int bBase = 16384 + ((wu * 32 + h) << 7) + pos16;       // W (u rows)

    auto COMPUTE = [&](int tau) {
        const char* s = L + (tau & 3) * 32768;
        bf16x8 wv[4], xv[8];
        #pragma unroll
        for (int i = 0; i < 4; ++i)
            wv[i] = *reinterpret_cast<const bf16x8*>(s + bBase + i * 1024);
        #pragma unroll
        for (int j = 0; j < 8; ++j)
            xv[j] = *reinterpret_cast<const bf16x8*>(s + aBase + j * 1024);
        __builtin_amdgcn_s_setprio(1);
        #pragma unroll
        for (int i = 0; i < 4; ++i)
            #pragma unroll
            for (int j = 0; j < 8; ++j)
                acc[i][j] = __builtin_amdgcn_mfma_f32_16x16x32_bf16(
                    wv[i], xv[j], acc[i][j], 0, 0, 0);
        __builtin_amdgcn_s_setprio(0);
    };

    // ---- 32-phase pipelined K loop ----
    STAGE(0); STAGE(1); STAGE(2);

    #pragma unroll 1
    for (int tau = 0; tau < 29; ++tau) {
        asm volatile("s_waitcnt vmcnt(8)" ::: "memory");
        __builtin_amdgcn_s_barrier();
        STAGE(tau + 3);
        COMPUTE(tau);
    }
    asm volatile("s_waitcnt vmcnt(8)" ::: "memory");
    __builtin_amdgcn_s_barrier();
    COMPUTE(29);
    asm volatile("s_waitcnt vmcnt(4)" ::: "memory");
    __builtin_amdgcn_s_barrier();
    COMPUTE(30);
    asm volatile("s_waitcnt vmcnt(0)" ::: "memory");
    __builtin_amdgcn_s_barrier();
    COMPUTE(31);

    // ---- epilogue: bias + activation + float4 stores ----
    // D layout: col = lane&15 -> m; row = (lane>>4)*4+reg -> u (4 consecutive)
    const int l15  = lane & 15;
    const int gate = ntile >> 1;                     // uniform per block
    float* __restrict__ outg = (gate == 0) ? zbuf : (gate == 1 ? fbuf : obuf);
    const float* __restrict__ bg = (gate == 0) ? bz : (gate == 1 ? bfg : bo);
    const int ubase = (ntile & 1) * 256 + wu * 64 + ((lane >> 4) << 2);
    const int mbase = m0 + wm * 128 + l15;

    #pragma unroll
    for (int i = 0; i < 4; ++i) {
        const int u = ubase + i * 16;
        const float4 b4 = *reinterpret_cast<const float4*>(bg + u);
        #pragma unroll
        for (int j = 0; j < 8; ++j) {
            const int m = mbase + j * 16;
            float4 v;
            v.x = acc[i][j][0] + b4.x;
            v.y = acc[i][j][1] + b4.y;
            v.z = acc[i][j][2] + b4.z;
            v.w = acc[i][j][3] + b4.w;
            if (gate == 0) {
                v.x = 2.0f / (1.0f + __expf(-2.0f * v.x)) - 1.0f;
                v.y = 2.0f / (1.0f + __expf(-2.0f * v.y)) - 1.0f;
                v.z = 2.0f / (1.0f + __expf(-2.0f * v.z)) - 1.0f;
                v.w = 2.0f / (1.0f + __expf(-2.0f * v.w)) - 1.0f;
            } else {
                v.x = 1.0f / (1.0f + __expf(-v.x));
                v.y = 1.0f / (1.0f + __expf(-v.y));
                v.z = 1.0f / (1.0f + __expf(-v.z));
                v.w = 1.0f / (1.0f + __expf(-v.w));
            }
            *reinterpret_cast<float4*>(outg + (size_t)m * 512 + u) = v;
        }
    }
}

// ---------------------------------------------------------------------------
// Phase 1: per-chunk affine summary.  One block per (b, chunk); each thread
// handles 2 consecutive u via float2 (2 KB contiguous per wave-row).
// ---------------------------------------------------------------------------
__global__ __launch_bounds__(256)
void chunk_summary_kernel(const float* __restrict__ fbuf,
                          const float* __restrict__ zbuf,
                          float* __restrict__ Ach, float* __restrict__ Bch)
{
    const int bc = blockIdx.x;           // 0..511
    const int c  = bc & (NCH - 1);
    const int b  = bc >> 5;              // NCH = 32
    const int u  = threadIdx.x * 2;

    const long long base = ((long long)(b * T_ + c * CHUNK)) * U_ + u;
    float2 A = make_float2(1.0f, 1.0f);
    float2 Bv = make_float2(0.0f, 0.0f);
    #pragma unroll 8
    for (int i = 0; i < CHUNK; ++i) {
        const float2 f = *reinterpret_cast<const float2*>(fbuf + base + (long long)i * U_);
        const float2 z = *reinterpret_cast<const float2*>(zbuf + base + (long long)i * U_);
        Bv.x = f.x * Bv.x + (1.0f - f.x) * z.x;
        Bv.y = f.y * Bv.y + (1.0f - f.y) * z.y;
        A.x *= f.x;
        A.y *= f.y;
    }
    const int idx = (b * NCH + c) * U_ + u;
    *reinterpret_cast<float2*>(Ach + idx) = A;
    *reinterpret_cast<float2*>(Bch + idx) = Bv;
}

// ---------------------------------------------------------------------------
// Phase 2: exclusive prefix over chunks per (b,u). float2 per thread.
// grid: 16 blocks x 256 threads = 4096 threads x 2 u = 8192 (b,u) pairs.
// ---------------------------------------------------------------------------
__global__ __launch_bounds__(256)
void chunk_prefix_kernel(const float* __restrict__ Ach,
                         const float* __restrict__ Bch,
                         float* __restrict__ Hin)
{
    const int g = blockIdx.x * 256 + threadIdx.x;   // 0..4095
    const int b = g >> 8;
    const int u = (g & 255) * 2;
    float2 h = make_float2(0.0f, 0.0f);
    #pragma unroll 4
    for (int c = 0; c < NCH; ++c) {
        const int idx = (b * NCH + c) * U_ + u;
        *reinterpret_cast<float2*>(Hin + idx) = h;
        const float2 A = *reinterpret_cast<const float2*>(Ach + idx);
        const float2 Bv = *reinterpret_cast<const float2*>(Bch + idx);
        h.x = A.x * h.x + Bv.x;
        h.y = A.y * h.y + Bv.y;
    }
}

// ---------------------------------------------------------------------------
// Phase 3: apply scan within chunk, multiply by o, write output. float2.
// ---------------------------------------------------------------------------
__global__ __launch_bounds__(256)
void scan_apply_kernel(const float* __restrict__ fbuf,
                       const float* __restrict__ zbuf,
                       const float* __restrict__ obuf,
                       const float* __restrict__ Hin,
                       float* __restrict__ out)
{
    const int bc = blockIdx.x;           // 0..511
    const int c  = bc & (NCH - 1);
    const int b  = bc >> 5;
    const int u  = threadIdx.x * 2;

    const long long base = ((long long)(b * T_ + c * CHUNK)) * U_ + u;
    float2 h = *reinterpret_cast<const float2*>(Hin + (b * NCH + c) * U_ + u);
    #pragma unroll 8
    for (int i = 0; i < CHUNK; ++i) {
        const long long p = base + (long long)i * U_;
        const float2 f = *reinterpret_cast<const float2*>(fbuf + p);
        const float2 z = *reinterpret_cast<const float2*>(zbuf + p);
        const float2 o = *reinterpret_cast<const float2*>(obuf + p);
        h.x = f.x * h.x + (1.0f - f.x) * z.x;
        h.y = f.y * h.y + (1.0f - f.y) * z.y;
        float2 r;
        r.x = o.x * h.x;
        r.y = o.y * h.y;
        *reinterpret_cast<float2*>(out + p) = r;
    }
}

// ---------------------------------------------------------------------------
extern "C" void kernel_launch(void* const* d_in, const int* in_sizes, int n_in,
                              void* d_out, int out_size, void* d_ws, size_t ws_size,
                              hipStream_t stream)
{
    const float* x  = (const float*)d_in[0];
    const float* Wz = (const float*)d_in[1];
    const float* bz = (const float*)d_in[2];
    const float* Wf = (const float*)d_in[3];
    const float* bf = (const float*)d_in[4];
    const float* Wo = (const float*)d_in[5];
    const float* bo = (const float*)d_in[6];
    float* out = (float*)d_out;

    const size_t S  = (size_t)M_ * U_;            // 33,554,432 per gate buffer
    const size_t Sc = (size_t)B_ * NCH * U_;      // 262,144 per chunk buffer
    const size_t XZ = (size_t)B_ * (T_ + 1) * D_; // 33,562,624 bf16 elems
    const size_t WT = (size_t)NTOT * KK;          // 1,572,864 bf16 elems

    float* zbuf = (float*)d_ws;
    float* fbuf = zbuf + S;
    float* obuf = fbuf + S;
    unsigned short* xz = (unsigned short*)(obuf + S);
    unsigned short* Wt = xz + XZ;
    float* Ach = (float*)(Wt + WT);
    float* Bch = Ach + Sc;
    float* Hin = Bch + Sc;

    const size_t need = 3 * S * sizeof(float) + (XZ + WT) * sizeof(unsigned short)
                      + 3 * Sc * sizeof(float);
    if (ws_size < need) {
        fprintf(stderr, "QRNN kernel: ws_size=%zu < needed %zu bytes!\n",
                ws_size, need);
    }

    // 1. converts
    {
        const size_t nthreads = XZ / 8;                   // 4,195,328
        convert_x_kernel<<<dim3((unsigned)(nthreads / 256)), 256, 0, stream>>>(x, xz);
        convert_wt_kernel<<<dim3(32, 16, 3), dim3(32, 8), 0, stream>>>(Wz, Wf, Wo, Wt);
    }
    // 2. pipelined bf16 MFMA GEMM + activations (256^2 tile, 4-slot ring)
    gemm_mfma_kernel<<<dim3(6 * (M_ / 256)), 512, 0, stream>>>(
        xz, Wt, bz, bf, bo, zbuf, fbuf, obuf);
    // 3. scan
    chunk_summary_kernel<<<dim3(B_ * NCH), 256, 0, stream>>>(fbuf, zbuf, Ach, Bch);
    chunk_prefix_kernel<<<dim3(16), 256, 0, stream>>>(Ach, Bch, Hin);
    scan_apply_kernel<<<dim3(B_ * NCH), 256, 0, stream>>>(fbuf, zbuf, obuf, Hin, out);
}